// Round 3
// baseline (473.639 us; speedup 1.0000x reference)
//
#include <hip/hip_runtime.h>
#include <stdint.h>
#include <math.h>

// GAT layer, restructured:
//   dst-term and b_attn cancel in softmax over j; masked exp()==0 exactly.
//   p_j = exp(src_j) (no max needed: |src|<~0.7), G = [p*hsum | p] in fp16,
//   out = (adj @ G_num) / (adj @ p) / n via f16 MFMA.
// R7: bit-pack adj. R6 post-mortem: k_agg(R0)==k_agg(R6)==~128us (2.1 TB/s adj
//     delivery) regardless of pipeline depth -> the GEMM-shaped adj read is
//     pattern/concurrency-limited, not fixable in-loop. New: streaming pass
//     (fused into k_feat launch, 1024 extra blocks, ballot-based) packs adj
//     0/1 -> 1 bit (268MB -> 8.4MB, L2-resident). k_agg expands bits->fp16
//     in registers (v_bfe+cndmask) and runs the IDENTICAL MFMA sequence ->
//     bitwise-same result. k_agg loses all staging/LDS.

#define Bz   4
#define Nn   4096
#define Dd   256
#define OUTd 64
#define GTR  80   // 64 hsum rows + 1 p row + 15 pad rows (poison; cols 65..79 ignored)
#define NT   32   // k_agg: K tiles of 128

typedef float    f32x4   __attribute__((ext_vector_type(4)));
typedef __fp16   fp16x2  __attribute__((ext_vector_type(2)));   // cvt_pkrtz return type
typedef _Float16 half8_t __attribute__((ext_vector_type(8)));

__device__ inline half8_t cvt8(float4 a, float4 b) {
  union { fp16x2 h2[4]; half8_t h8; } r;
  r.h2[0] = __builtin_amdgcn_cvt_pkrtz(a.x, a.y);
  r.h2[1] = __builtin_amdgcn_cvt_pkrtz(a.z, a.w);
  r.h2[2] = __builtin_amdgcn_cvt_pkrtz(b.x, b.y);
  r.h2[3] = __builtin_amdgcn_cvt_pkrtz(b.z, b.w);
  return r.h8;
}

// expand 8 bits -> 8 fp16 values in {0.0, 1.0} (exact)
__device__ inline half8_t expand8(unsigned int byte) {
  half8_t e;
  #pragma unroll
  for (int r = 0; r < 8; ++r)
    e[r] = (_Float16)(float)((byte >> r) & 1u);
  return e;
}

// ---- prep (merged): Ut rows 0..63 (head-summed W_fc), Ut row 64 (src vector),
//      hb[l] = sum_h b_fc, sb = b_fc . w_s.  w_s recomputed in blocks 64/65.
__global__ __launch_bounds__(256) void k_prep(const float* __restrict__ W_fc,
                                              const float* __restrict__ W_attn,
                                              const float* __restrict__ b_fc,
                                              _Float16* __restrict__ Ut,
                                              float* __restrict__ hb,
                                              float* __restrict__ sb) {
  const int bx = blockIdx.x, t = threadIdx.x;
  if (bx < 64) {
    const int l = bx, d = t;
    float v = W_fc[l * 256 + d] + W_fc[(64 + l) * 256 + d] +
              W_fc[(128 + l) * 256 + d] + W_fc[(192 + l) * 256 + d];
    Ut[l * 256 + d] = (_Float16)v;
    return;
  }
  __shared__ float ws_sh[256];   // w_s[ho], ho = h*64+o
  {
    const int h = t >> 6, o = t & 63;
    float s = 0.f;
    for (int k = 0; k < 4; ++k) s += W_attn[k * 512 + h * 128 + o];
    ws_sh[t] = s * 0.25f;
  }
  __syncthreads();
  if (bx == 64) {
    const int d = t;
    float v = 0.f;
    for (int ho = 0; ho < 256; ++ho) v += W_fc[ho * 256 + d] * ws_sh[ho];
    Ut[64 * 256 + d] = (_Float16)v;
  } else {
    __shared__ float red[256];
    red[t] = b_fc[t] * ws_sh[t];
    if (t < 64) hb[t] = b_fc[t] + b_fc[64 + t] + b_fc[128 + t] + b_fc[192 + t];
    __syncthreads();
    if (t == 0) {
      float a = 0.f;
      for (int i = 0; i < 256; ++i) a += red[i];
      *sb = a;
    }
  }
}

// ---- fused stage 1:
//  blocks [0,256):   Gt[b][l][j] = fp16(p_j * hsum_lj), Gt[b][64][j] = fp16(p_j)
//  blocks [256,1280): pack adj rows to bits: Pk[row][w] bit l = adj[row][w*64+l]
__global__ __launch_bounds__(256) void k_featpack(const float* __restrict__ feat,
                                                  const float* __restrict__ adj,
                                                  const _Float16* __restrict__ Ut,
                                                  const float* __restrict__ hb,
                                                  const float* __restrict__ sb,
                                                  _Float16* __restrict__ Gt,
                                                  unsigned long long* __restrict__ Pk) {
  const int bx = blockIdx.x;
  const int tid = threadIdx.x;
  const int lane = tid & 63;
  const int wv = tid >> 6;

  if (bx >= 256) {
    // ---- pack path: 1024 blocks x 4 waves; each wave packs 4 rows.
    const int gw = (bx - 256) * 4 + wv;          // 0..4095
    #pragma unroll 1
    for (int rr = 0; rr < 4; ++rr) {
      const size_t row = (size_t)gw * 4 + rr;    // 0..16383 (= b*Nn + i)
      const float* arow = adj + row * (size_t)Nn + lane;
      unsigned long long myw = 0ull;
      #pragma unroll 4
      for (int wi = 0; wi < 64; ++wi) {
        float v = arow[(size_t)wi * 64];
        unsigned long long bal = __ballot(v != 0.0f);
        if (lane == wi) myw = bal;               // wave-uniform bal -> lane wi keeps word wi
      }
      Pk[row * 64 + lane] = myw;                 // 512 B coalesced per row
    }
    return;
  }

  // ---- feat path (identical math to previous rounds)
  const int b = bx >> 6;
  const int jblk = bx & 63;
  const int ln15 = lane & 15;
  const int quad = lane >> 4;
  const int j = jblk * 64 + wv * 16 + ln15;

  const float* frow = feat + ((size_t)b * Nn + j) * Dd + quad * 8;
  f32x4 acc0 = {0,0,0,0}, acc1 = {0,0,0,0}, acc2 = {0,0,0,0}, acc3 = {0,0,0,0}, acc4 = {0,0,0,0};

  #pragma unroll
  for (int d0 = 0; d0 < Dd; d0 += 32) {
    float4 F0 = *(const float4*)(frow + d0);
    float4 F1 = *(const float4*)(frow + d0 + 4);
    half8_t bf = cvt8(F0, F1);
    const _Float16* up = Ut + (size_t)ln15 * Dd + d0 + quad * 8;
    acc0 = __builtin_amdgcn_mfma_f32_16x16x32_f16(*(const half8_t*)(up + 0 * 16 * Dd), bf, acc0, 0, 0, 0);
    acc1 = __builtin_amdgcn_mfma_f32_16x16x32_f16(*(const half8_t*)(up + 1 * 16 * Dd), bf, acc1, 0, 0, 0);
    acc2 = __builtin_amdgcn_mfma_f32_16x16x32_f16(*(const half8_t*)(up + 2 * 16 * Dd), bf, acc2, 0, 0, 0);
    acc3 = __builtin_amdgcn_mfma_f32_16x16x32_f16(*(const half8_t*)(up + 3 * 16 * Dd), bf, acc3, 0, 0, 0);
    acc4 = __builtin_amdgcn_mfma_f32_16x16x32_f16(*(const half8_t*)(up + 4 * 16 * Dd), bf, acc4, 0, 0, 0);
  }
  float srcv = __shfl(acc4[0], ln15) + sb[0];
  float p = expf(srcv);
  _Float16* gb = Gt + (size_t)b * GTR * Nn;
  #pragma unroll
  for (int r = 0; r < 4; ++r) {
    int lb = quad * 4 + r;
    gb[(size_t)(0  + lb) * Nn + j] = (_Float16)((acc0[r] + hb[0  + lb]) * p);
    gb[(size_t)(16 + lb) * Nn + j] = (_Float16)((acc1[r] + hb[16 + lb]) * p);
    gb[(size_t)(32 + lb) * Nn + j] = (_Float16)((acc2[r] + hb[32 + lb]) * p);
    gb[(size_t)(48 + lb) * Nn + j] = (_Float16)((acc3[r] + hb[48 + lb]) * p);
  }
  if (quad == 0) gb[(size_t)64 * Nn + j] = (_Float16)p;
}

// ---- stage 2: out[b][i][l] = (adj[b] @ Gt^T)[i][l] / (adj[b] @ p)[i] / n
// adj comes from the 8.4 MB bit matrix (L2-resident): per tile each lane loads
// one uint4 (128 bits = BK=128 cols of its row) and expands its byte per
// K-subtile to a fp16 0/1 fragment. MFMA order identical to R6 -> bitwise
// identical output.
__global__ __launch_bounds__(256) void k_agg(const uint4* __restrict__ Pk,
                                             const _Float16* __restrict__ Gt,
                                             float* __restrict__ out) {
  const int b = blockIdx.y;
  const int tid = threadIdx.x;
  const int lane = tid & 63;
  const int wv = tid >> 6;
  const int ln15 = lane & 15;
  const int quad = lane >> 4;
  const int i0 = blockIdx.x * 64 + wv * 16;

  const uint4* prow = Pk + ((size_t)b * Nn + i0 + ln15) * 32;   // 32 uint4 per packed row

  const _Float16* g0 = Gt + ((size_t)b * GTR + ln15) * Nn + quad * 8;
  const _Float16* g1 = g0 + (size_t)16 * Nn;
  const _Float16* g2 = g0 + (size_t)32 * Nn;
  const _Float16* g3 = g0 + (size_t)48 * Nn;
  const _Float16* g4 = g0 + (size_t)64 * Nn;

  f32x4 acc0 = {0,0,0,0}, acc1 = {0,0,0,0}, acc2 = {0,0,0,0}, acc3 = {0,0,0,0}, acc4 = {0,0,0,0};

  #pragma unroll 2
  for (int t = 0; t < NT; ++t) {
    const int k0 = t * 128;
    uint4 w4 = prow[t];                          // bits for cols k0..k0+127
    half8_t bg0[4], bg1[4], bg2[4], bg3[4], bg4[4];
    #pragma unroll
    for (int s = 0; s < 4; ++s) {
      const int kk = k0 + s * 32;
      bg0[s] = *(const half8_t*)(g0 + kk);
      bg1[s] = *(const half8_t*)(g1 + kk);
      bg2[s] = *(const half8_t*)(g2 + kk);
      bg3[s] = *(const half8_t*)(g3 + kk);
      bg4[s] = *(const half8_t*)(g4 + kk);
    }
    #pragma unroll
    for (int s = 0; s < 4; ++s) {
      const unsigned int word = (s == 0) ? w4.x : (s == 1) ? w4.y : (s == 2) ? w4.z : w4.w;
      half8_t aF = expand8((word >> (quad * 8)) & 0xffu);
      acc0 = __builtin_amdgcn_mfma_f32_16x16x32_f16(aF, bg0[s], acc0, 0, 0, 0);
      acc1 = __builtin_amdgcn_mfma_f32_16x16x32_f16(aF, bg1[s], acc1, 0, 0, 0);
      acc2 = __builtin_amdgcn_mfma_f32_16x16x32_f16(aF, bg2[s], acc2, 0, 0, 0);
      acc3 = __builtin_amdgcn_mfma_f32_16x16x32_f16(aF, bg3[s], acc3, 0, 0, 0);
      acc4 = __builtin_amdgcn_mfma_f32_16x16x32_f16(aF, bg4[s], acc4, 0, 0, 0);
    }
  }

  // denominator (col 64 = tile4 local col 0) held by lane (lane & 48); broadcast per row
  float den0 = __shfl(acc4[0], lane & 48);
  float den1 = __shfl(acc4[1], lane & 48);
  float den2 = __shfl(acc4[2], lane & 48);
  float den3 = __shfl(acc4[3], lane & 48);
  const float invn = 1.0f / (float)Nn;
  float* orow = out + ((size_t)b * Nn + i0) * OUTd;
  #pragma unroll
  for (int r = 0; r < 4; ++r) {
    float d = (r == 0) ? den0 : (r == 1) ? den1 : (r == 2) ? den2 : den3;
    float rd = invn / d;
    int ir = quad * 4 + r;
    orow[(size_t)ir * OUTd + 0  + ln15] = acc0[r] * rd;
    orow[(size_t)ir * OUTd + 16 + ln15] = acc1[r] * rd;
    orow[(size_t)ir * OUTd + 32 + ln15] = acc2[r] * rd;
    orow[(size_t)ir * OUTd + 48 + ln15] = acc3[r] * rd;
  }
}

extern "C" void kernel_launch(void* const* d_in, const int* in_sizes, int n_in,
                              void* d_out, int out_size, void* d_ws, size_t ws_size,
                              hipStream_t stream) {
  const float* feat   = (const float*)d_in[0];
  const float* adj    = (const float*)d_in[1];
  const float* W_fc   = (const float*)d_in[2];
  const float* b_fc   = (const float*)d_in[3];
  const float* W_attn = (const float*)d_in[4];
  (void)d_in[5]; // b_attn cancels in softmax
  float* out = (float*)d_out;

  char* ws = (char*)d_ws;
  _Float16* Gt = (_Float16*)ws;                               // 4*80*4096*2 = 2,621,440 B
  _Float16* Ut = (_Float16*)(ws + 2621440);                   // 80*256*2   =    40,960 B
  float*    hb  = (float*)(ws + 2621440 + 40960);             // 256 B
  float*    sb  = (float*)(ws + 2621440 + 40960 + 256);       // 4 B
  unsigned long long* Pk = (unsigned long long*)(ws + 4194304); // 16384*64*8 = 8,388,608 B

  k_prep<<<66, 256, 0, stream>>>(W_fc, W_attn, b_fc, Ut, hb, sb);
  k_featpack<<<1280, 256, 0, stream>>>(feat, adj, Ut, hb, sb, Gt, Pk);
  k_agg<<<dim3(64, 4), 256, 0, stream>>>((const uint4*)Pk, Gt, out);
}

// Round 4
// 461.212 us; speedup vs baseline: 1.0269x; 1.0269x over previous
//
#include <hip/hip_runtime.h>
#include <stdint.h>
#include <math.h>

// GAT layer, restructured:
//   dst-term and b_attn cancel in softmax over j; masked exp()==0 exactly.
//   p_j = exp(src_j) (no max needed: |src|<~0.7), G = [p*hsum | p] in fp16,
//   out = (adj @ G_num) / (adj @ p) / n via f16 MFMA.
// R8: fix the pack pass. R7's ballot packer serialized (scalar loads + 64
//     cross-lane ballots per row) -> est 150-200us. New pack: 1 thread per
//     uint32 word; 8 independent float4 loads (128B contiguous per thread),
//     per-lane bit assembly (no cross-lane), 1 coalesced store. Same Pk bit
//     layout as R7 -> k_agg unchanged, bitwise-identical output.

#define Bz   4
#define Nn   4096
#define Dd   256
#define OUTd 64
#define GTR  80   // 64 hsum rows + 1 p row + 15 pad rows (poison; cols 65..79 ignored)
#define NT   32   // k_agg: K tiles of 128

typedef float    f32x4   __attribute__((ext_vector_type(4)));
typedef __fp16   fp16x2  __attribute__((ext_vector_type(2)));   // cvt_pkrtz return type
typedef _Float16 half8_t __attribute__((ext_vector_type(8)));

__device__ inline half8_t cvt8(float4 a, float4 b) {
  union { fp16x2 h2[4]; half8_t h8; } r;
  r.h2[0] = __builtin_amdgcn_cvt_pkrtz(a.x, a.y);
  r.h2[1] = __builtin_amdgcn_cvt_pkrtz(a.z, a.w);
  r.h2[2] = __builtin_amdgcn_cvt_pkrtz(b.x, b.y);
  r.h2[3] = __builtin_amdgcn_cvt_pkrtz(b.z, b.w);
  return r.h8;
}

// expand 8 bits -> 8 fp16 values in {0.0, 1.0} (exact)
__device__ inline half8_t expand8(unsigned int byte) {
  half8_t e;
  #pragma unroll
  for (int r = 0; r < 8; ++r)
    e[r] = (_Float16)(float)((byte >> r) & 1u);
  return e;
}

// ---- prep (merged): Ut rows 0..63 (head-summed W_fc), Ut row 64 (src vector),
//      hb[l] = sum_h b_fc, sb = b_fc . w_s.  w_s recomputed in blocks 64/65.
__global__ __launch_bounds__(256) void k_prep(const float* __restrict__ W_fc,
                                              const float* __restrict__ W_attn,
                                              const float* __restrict__ b_fc,
                                              _Float16* __restrict__ Ut,
                                              float* __restrict__ hb,
                                              float* __restrict__ sb) {
  const int bx = blockIdx.x, t = threadIdx.x;
  if (bx < 64) {
    const int l = bx, d = t;
    float v = W_fc[l * 256 + d] + W_fc[(64 + l) * 256 + d] +
              W_fc[(128 + l) * 256 + d] + W_fc[(192 + l) * 256 + d];
    Ut[l * 256 + d] = (_Float16)v;
    return;
  }
  __shared__ float ws_sh[256];   // w_s[ho], ho = h*64+o
  {
    const int h = t >> 6, o = t & 63;
    float s = 0.f;
    for (int k = 0; k < 4; ++k) s += W_attn[k * 512 + h * 128 + o];
    ws_sh[t] = s * 0.25f;
  }
  __syncthreads();
  if (bx == 64) {
    const int d = t;
    float v = 0.f;
    for (int ho = 0; ho < 256; ++ho) v += W_fc[ho * 256 + d] * ws_sh[ho];
    Ut[64 * 256 + d] = (_Float16)v;
  } else {
    __shared__ float red[256];
    red[t] = b_fc[t] * ws_sh[t];
    if (t < 64) hb[t] = b_fc[t] + b_fc[64 + t] + b_fc[128 + t] + b_fc[192 + t];
    __syncthreads();
    if (t == 0) {
      float a = 0.f;
      for (int i = 0; i < 256; ++i) a += red[i];
      *sb = a;
    }
  }
}

// ---- fused stage 1:
//  blocks [0,256):    Gt[b][l][j] = fp16(p_j * hsum_lj), Gt[b][64][j] = fp16(p_j)
//  blocks [256,8448): streaming bit-pack of adj. One thread per uint32 word:
//                     Pk32[row*128+c] bit p = (adj[row][c*32+p] != 0).
__global__ __launch_bounds__(256) void k_featpack(const float* __restrict__ feat,
                                                  const float* __restrict__ adj,
                                                  const _Float16* __restrict__ Ut,
                                                  const float* __restrict__ hb,
                                                  const float* __restrict__ sb,
                                                  _Float16* __restrict__ Gt,
                                                  unsigned int* __restrict__ Pk32) {
  const int bx = blockIdx.x;
  const int tid = threadIdx.x;

  if (bx >= 256) {
    // ---- pack path: pure streaming, no cross-lane ops.
    const int t = (bx - 256) * 256 + tid;        // 0 .. 2,097,151
    const size_t row = (size_t)(t >> 7);         // 0..16383 (= b*Nn + i)
    const int c = t & 127;                       // word index within row
    const float4* src = (const float4*)(adj + row * (size_t)Nn + c * 32);
    unsigned int w = 0;
    #pragma unroll
    for (int q = 0; q < 8; ++q) {
      float4 v = src[q];
      w |= (v.x != 0.0f ? 1u : 0u) << (q * 4 + 0);
      w |= (v.y != 0.0f ? 1u : 0u) << (q * 4 + 1);
      w |= (v.z != 0.0f ? 1u : 0u) << (q * 4 + 2);
      w |= (v.w != 0.0f ? 1u : 0u) << (q * 4 + 3);
    }
    Pk32[row * 128 + c] = w;
    return;
  }

  // ---- feat path (identical math to previous rounds)
  const int lane = tid & 63;
  const int wv = tid >> 6;
  const int b = bx >> 6;
  const int jblk = bx & 63;
  const int ln15 = lane & 15;
  const int quad = lane >> 4;
  const int j = jblk * 64 + wv * 16 + ln15;

  const float* frow = feat + ((size_t)b * Nn + j) * Dd + quad * 8;
  f32x4 acc0 = {0,0,0,0}, acc1 = {0,0,0,0}, acc2 = {0,0,0,0}, acc3 = {0,0,0,0}, acc4 = {0,0,0,0};

  #pragma unroll
  for (int d0 = 0; d0 < Dd; d0 += 32) {
    float4 F0 = *(const float4*)(frow + d0);
    float4 F1 = *(const float4*)(frow + d0 + 4);
    half8_t bf = cvt8(F0, F1);
    const _Float16* up = Ut + (size_t)ln15 * Dd + d0 + quad * 8;
    acc0 = __builtin_amdgcn_mfma_f32_16x16x32_f16(*(const half8_t*)(up + 0 * 16 * Dd), bf, acc0, 0, 0, 0);
    acc1 = __builtin_amdgcn_mfma_f32_16x16x32_f16(*(const half8_t*)(up + 1 * 16 * Dd), bf, acc1, 0, 0, 0);
    acc2 = __builtin_amdgcn_mfma_f32_16x16x32_f16(*(const half8_t*)(up + 2 * 16 * Dd), bf, acc2, 0, 0, 0);
    acc3 = __builtin_amdgcn_mfma_f32_16x16x32_f16(*(const half8_t*)(up + 3 * 16 * Dd), bf, acc3, 0, 0, 0);
    acc4 = __builtin_amdgcn_mfma_f32_16x16x32_f16(*(const half8_t*)(up + 4 * 16 * Dd), bf, acc4, 0, 0, 0);
  }
  float srcv = __shfl(acc4[0], ln15) + sb[0];
  float p = expf(srcv);
  _Float16* gb = Gt + (size_t)b * GTR * Nn;
  #pragma unroll
  for (int r = 0; r < 4; ++r) {
    int lb = quad * 4 + r;
    gb[(size_t)(0  + lb) * Nn + j] = (_Float16)((acc0[r] + hb[0  + lb]) * p);
    gb[(size_t)(16 + lb) * Nn + j] = (_Float16)((acc1[r] + hb[16 + lb]) * p);
    gb[(size_t)(32 + lb) * Nn + j] = (_Float16)((acc2[r] + hb[32 + lb]) * p);
    gb[(size_t)(48 + lb) * Nn + j] = (_Float16)((acc3[r] + hb[48 + lb]) * p);
  }
  if (quad == 0) gb[(size_t)64 * Nn + j] = (_Float16)p;
}

// ---- stage 2: out[b][i][l] = (adj[b] @ Gt^T)[i][l] / (adj[b] @ p)[i] / n
// adj comes from the 8.4 MB bit matrix (L2-resident): per tile each lane loads
// one uint4 (128 bits = BK=128 cols of its row) and expands its byte per
// K-subtile to a fp16 0/1 fragment. MFMA order identical to R6 -> bitwise
// identical output.
__global__ __launch_bounds__(256) void k_agg(const uint4* __restrict__ Pk,
                                             const _Float16* __restrict__ Gt,
                                             float* __restrict__ out) {
  const int b = blockIdx.y;
  const int tid = threadIdx.x;
  const int lane = tid & 63;
  const int wv = tid >> 6;
  const int ln15 = lane & 15;
  const int quad = lane >> 4;
  const int i0 = blockIdx.x * 64 + wv * 16;

  const uint4* prow = Pk + ((size_t)b * Nn + i0 + ln15) * 32;   // 32 uint4 per packed row

  const _Float16* g0 = Gt + ((size_t)b * GTR + ln15) * Nn + quad * 8;
  const _Float16* g1 = g0 + (size_t)16 * Nn;
  const _Float16* g2 = g0 + (size_t)32 * Nn;
  const _Float16* g3 = g0 + (size_t)48 * Nn;
  const _Float16* g4 = g0 + (size_t)64 * Nn;

  f32x4 acc0 = {0,0,0,0}, acc1 = {0,0,0,0}, acc2 = {0,0,0,0}, acc3 = {0,0,0,0}, acc4 = {0,0,0,0};

  #pragma unroll 2
  for (int t = 0; t < NT; ++t) {
    const int k0 = t * 128;
    uint4 w4 = prow[t];                          // bits for cols k0..k0+127
    half8_t bg0[4], bg1[4], bg2[4], bg3[4], bg4[4];
    #pragma unroll
    for (int s = 0; s < 4; ++s) {
      const int kk = k0 + s * 32;
      bg0[s] = *(const half8_t*)(g0 + kk);
      bg1[s] = *(const half8_t*)(g1 + kk);
      bg2[s] = *(const half8_t*)(g2 + kk);
      bg3[s] = *(const half8_t*)(g3 + kk);
      bg4[s] = *(const half8_t*)(g4 + kk);
    }
    #pragma unroll
    for (int s = 0; s < 4; ++s) {
      const unsigned int word = (s == 0) ? w4.x : (s == 1) ? w4.y : (s == 2) ? w4.z : w4.w;
      half8_t aF = expand8((word >> (quad * 8)) & 0xffu);
      acc0 = __builtin_amdgcn_mfma_f32_16x16x32_f16(aF, bg0[s], acc0, 0, 0, 0);
      acc1 = __builtin_amdgcn_mfma_f32_16x16x32_f16(aF, bg1[s], acc1, 0, 0, 0);
      acc2 = __builtin_amdgcn_mfma_f32_16x16x32_f16(aF, bg2[s], acc2, 0, 0, 0);
      acc3 = __builtin_amdgcn_mfma_f32_16x16x32_f16(aF, bg3[s], acc3, 0, 0, 0);
      acc4 = __builtin_amdgcn_mfma_f32_16x16x32_f16(aF, bg4[s], acc4, 0, 0, 0);
    }
  }

  // denominator (col 64 = tile4 local col 0) held by lane (lane & 48); broadcast per row
  float den0 = __shfl(acc4[0], lane & 48);
  float den1 = __shfl(acc4[1], lane & 48);
  float den2 = __shfl(acc4[2], lane & 48);
  float den3 = __shfl(acc4[3], lane & 48);
  const float invn = 1.0f / (float)Nn;
  float* orow = out + ((size_t)b * Nn + i0) * OUTd;
  #pragma unroll
  for (int r = 0; r < 4; ++r) {
    float d = (r == 0) ? den0 : (r == 1) ? den1 : (r == 2) ? den2 : den3;
    float rd = invn / d;
    int ir = quad * 4 + r;
    orow[(size_t)ir * OUTd + 0  + ln15] = acc0[r] * rd;
    orow[(size_t)ir * OUTd + 16 + ln15] = acc1[r] * rd;
    orow[(size_t)ir * OUTd + 32 + ln15] = acc2[r] * rd;
    orow[(size_t)ir * OUTd + 48 + ln15] = acc3[r] * rd;
  }
}

extern "C" void kernel_launch(void* const* d_in, const int* in_sizes, int n_in,
                              void* d_out, int out_size, void* d_ws, size_t ws_size,
                              hipStream_t stream) {
  const float* feat   = (const float*)d_in[0];
  const float* adj    = (const float*)d_in[1];
  const float* W_fc   = (const float*)d_in[2];
  const float* b_fc   = (const float*)d_in[3];
  const float* W_attn = (const float*)d_in[4];
  (void)d_in[5]; // b_attn cancels in softmax
  float* out = (float*)d_out;

  char* ws = (char*)d_ws;
  _Float16* Gt = (_Float16*)ws;                               // 4*80*4096*2 = 2,621,440 B
  _Float16* Ut = (_Float16*)(ws + 2621440);                   // 80*256*2   =    40,960 B
  float*    hb  = (float*)(ws + 2621440 + 40960);             // 256 B
  float*    sb  = (float*)(ws + 2621440 + 40960 + 256);       // 4 B
  unsigned int* Pk32 = (unsigned int*)(ws + 4194304);         // 16384*128*4 = 8,388,608 B

  k_prep<<<66, 256, 0, stream>>>(W_fc, W_attn, b_fc, Ut, hb, sb);
  k_featpack<<<8448, 256, 0, stream>>>(feat, adj, Ut, hb, sb, Gt, Pk32);
  k_agg<<<dim3(64, 4), 256, 0, stream>>>((const uint4*)Pk32, Gt, out);
}

// Round 5
// 460.991 us; speedup vs baseline: 1.0274x; 1.0005x over previous
//
#include <hip/hip_runtime.h>
#include <stdint.h>
#include <math.h>

// GAT layer, restructured:
//   dst-term and b_attn cancel in softmax over j; masked exp()==0 exactly.
//   p_j = exp(src_j) (no max needed: |src|<~0.7), G = [p*hsum | p] in fp16,
//   out = (adj @ G_num) / (adj @ p) / n via f16 MFMA.
// R9: coalescing A/B test on the pack path. Ledger: every adj reader so far is
//     per-instruction segment-fragmented (R8: 16B/lane @ stride 128B = 64
//     lines/instr) and all cap at 0.9-2.1 TB/s, while contiguous writers/copies
//     hit 6.3-6.7 TB/s. New pack: lane l reads base+l*16 (1KB contiguous per
//     instruction, 8 instr per 2048-col half-row), transpose through
//     wave-private LDS (stride 34 -> <=4-way conflicts), assemble the SAME
//     uint32 word as R8. Pk layout + k_agg + k_feat + k_prep byte-identical
//     to R8 -> bitwise-same output.

#define Bz   4
#define Nn   4096
#define Dd   256
#define OUTd 64
#define GTR  80   // 64 hsum rows + 1 p row + 15 pad rows (poison; cols 65..79 ignored)
#define NT   32   // k_agg: K tiles of 128

typedef float    f32x4   __attribute__((ext_vector_type(4)));
typedef __fp16   fp16x2  __attribute__((ext_vector_type(2)));   // cvt_pkrtz return type
typedef _Float16 half8_t __attribute__((ext_vector_type(8)));

__device__ inline half8_t cvt8(float4 a, float4 b) {
  union { fp16x2 h2[4]; half8_t h8; } r;
  r.h2[0] = __builtin_amdgcn_cvt_pkrtz(a.x, a.y);
  r.h2[1] = __builtin_amdgcn_cvt_pkrtz(a.z, a.w);
  r.h2[2] = __builtin_amdgcn_cvt_pkrtz(b.x, b.y);
  r.h2[3] = __builtin_amdgcn_cvt_pkrtz(b.z, b.w);
  return r.h8;
}

// expand 8 bits -> 8 fp16 values in {0.0, 1.0} (exact)
__device__ inline half8_t expand8(unsigned int byte) {
  half8_t e;
  #pragma unroll
  for (int r = 0; r < 8; ++r)
    e[r] = (_Float16)(float)((byte >> r) & 1u);
  return e;
}

// ---- prep (merged): Ut rows 0..63 (head-summed W_fc), Ut row 64 (src vector),
//      hb[l] = sum_h b_fc, sb = b_fc . w_s.  w_s recomputed in blocks 64/65.
__global__ __launch_bounds__(256) void k_prep(const float* __restrict__ W_fc,
                                              const float* __restrict__ W_attn,
                                              const float* __restrict__ b_fc,
                                              _Float16* __restrict__ Ut,
                                              float* __restrict__ hb,
                                              float* __restrict__ sb) {
  const int bx = blockIdx.x, t = threadIdx.x;
  if (bx < 64) {
    const int l = bx, d = t;
    float v = W_fc[l * 256 + d] + W_fc[(64 + l) * 256 + d] +
              W_fc[(128 + l) * 256 + d] + W_fc[(192 + l) * 256 + d];
    Ut[l * 256 + d] = (_Float16)v;
    return;
  }
  __shared__ float ws_sh[256];   // w_s[ho], ho = h*64+o
  {
    const int h = t >> 6, o = t & 63;
    float s = 0.f;
    for (int k = 0; k < 4; ++k) s += W_attn[k * 512 + h * 128 + o];
    ws_sh[t] = s * 0.25f;
  }
  __syncthreads();
  if (bx == 64) {
    const int d = t;
    float v = 0.f;
    for (int ho = 0; ho < 256; ++ho) v += W_fc[ho * 256 + d] * ws_sh[ho];
    Ut[64 * 256 + d] = (_Float16)v;
  } else {
    __shared__ float red[256];
    red[t] = b_fc[t] * ws_sh[t];
    if (t < 64) hb[t] = b_fc[t] + b_fc[64 + t] + b_fc[128 + t] + b_fc[192 + t];
    __syncthreads();
    if (t == 0) {
      float a = 0.f;
      for (int i = 0; i < 256; ++i) a += red[i];
      *sb = a;
    }
  }
}

// ---- fused stage 1:
//  blocks [0,256):    Gt[b][l][j] = fp16(p_j * hsum_lj), Gt[b][64][j] = fp16(p_j)
//  blocks [256,8448): coalesced bit-pack of adj. One wave per 2048-col
//                     half-row; loads contiguous, LDS wave-transpose, then
//                     each lane emits one uint32 (same layout as R8):
//                     Pk32[row*128+c] bit p = (adj[row][c*32+p] != 0).
__global__ __launch_bounds__(256) void k_featpack(const float* __restrict__ feat,
                                                  const float* __restrict__ adj,
                                                  const _Float16* __restrict__ Ut,
                                                  const float* __restrict__ hb,
                                                  const float* __restrict__ sb,
                                                  _Float16* __restrict__ Gt,
                                                  unsigned int* __restrict__ Pk32) {
  __shared__ float xp[4][2178];                  // per-wave 64x34 transpose pad
  const int bx = blockIdx.x;
  const int tid = threadIdx.x;
  const int lane = tid & 63;
  const int wv = tid >> 6;

  if (bx >= 256) {
    // ---- pack path: per-instruction-contiguous loads (1KB/instr).
    const int H = (bx - 256) * 4 + wv;           // half-row id, 0..32767
    const size_t row = (size_t)(H >> 1);         // 0..16383 (= b*Nn + i)
    const int h = H & 1;
    const float4* src = (const float4*)(adj + row * (size_t)Nn + h * 2048);
    float4 v[8];
    #pragma unroll
    for (int q = 0; q < 8; ++q)
      v[q] = src[q * 64 + lane];                 // lane-contiguous: 64 lanes x 16B

    // transpose: float f (half-row idx q*256+lane*4+j) -> X[f>>5][f&31]
    float* X = xp[wv];
    #pragma unroll
    for (int q = 0; q < 8; ++q) {
      float* dst = X + (q * 8 + (lane >> 3)) * 34 + (lane & 7) * 4;
      *(float2*)(dst + 0) = *(const float2*)(&v[q].x);
      *(float2*)(dst + 2) = *(const float2*)(&v[q].z);
    }
    __builtin_amdgcn_s_waitcnt(0);               // wave-private LDS: just drain lgkm
    const float* Xr = X + lane * 34;             // word `lane`: floats lane*32..+31
    unsigned int w = 0;
    #pragma unroll
    for (int q = 0; q < 8; ++q) {
      float2 a = *(const float2*)(Xr + q * 4);
      float2 bfv = *(const float2*)(Xr + q * 4 + 2);
      w |= (a.x   != 0.0f ? 1u : 0u) << (q * 4 + 0);
      w |= (a.y   != 0.0f ? 1u : 0u) << (q * 4 + 1);
      w |= (bfv.x != 0.0f ? 1u : 0u) << (q * 4 + 2);
      w |= (bfv.y != 0.0f ? 1u : 0u) << (q * 4 + 3);
    }
    Pk32[row * 128 + h * 64 + lane] = w;         // coalesced 256B per wave
    return;
  }

  // ---- feat path (identical math to previous rounds)
  const int b = bx >> 6;
  const int jblk = bx & 63;
  const int ln15 = lane & 15;
  const int quad = lane >> 4;
  const int j = jblk * 64 + wv * 16 + ln15;

  const float* frow = feat + ((size_t)b * Nn + j) * Dd + quad * 8;
  f32x4 acc0 = {0,0,0,0}, acc1 = {0,0,0,0}, acc2 = {0,0,0,0}, acc3 = {0,0,0,0}, acc4 = {0,0,0,0};

  #pragma unroll
  for (int d0 = 0; d0 < Dd; d0 += 32) {
    float4 F0 = *(const float4*)(frow + d0);
    float4 F1 = *(const float4*)(frow + d0 + 4);
    half8_t bf = cvt8(F0, F1);
    const _Float16* up = Ut + (size_t)ln15 * Dd + d0 + quad * 8;
    acc0 = __builtin_amdgcn_mfma_f32_16x16x32_f16(*(const half8_t*)(up + 0 * 16 * Dd), bf, acc0, 0, 0, 0);
    acc1 = __builtin_amdgcn_mfma_f32_16x16x32_f16(*(const half8_t*)(up + 1 * 16 * Dd), bf, acc1, 0, 0, 0);
    acc2 = __builtin_amdgcn_mfma_f32_16x16x32_f16(*(const half8_t*)(up + 2 * 16 * Dd), bf, acc2, 0, 0, 0);
    acc3 = __builtin_amdgcn_mfma_f32_16x16x32_f16(*(const half8_t*)(up + 3 * 16 * Dd), bf, acc3, 0, 0, 0);
    acc4 = __builtin_amdgcn_mfma_f32_16x16x32_f16(*(const half8_t*)(up + 4 * 16 * Dd), bf, acc4, 0, 0, 0);
  }
  float srcv = __shfl(acc4[0], ln15) + sb[0];
  float p = expf(srcv);
  _Float16* gb = Gt + (size_t)b * GTR * Nn;
  #pragma unroll
  for (int r = 0; r < 4; ++r) {
    int lb = quad * 4 + r;
    gb[(size_t)(0  + lb) * Nn + j] = (_Float16)((acc0[r] + hb[0  + lb]) * p);
    gb[(size_t)(16 + lb) * Nn + j] = (_Float16)((acc1[r] + hb[16 + lb]) * p);
    gb[(size_t)(32 + lb) * Nn + j] = (_Float16)((acc2[r] + hb[32 + lb]) * p);
    gb[(size_t)(48 + lb) * Nn + j] = (_Float16)((acc3[r] + hb[48 + lb]) * p);
  }
  if (quad == 0) gb[(size_t)64 * Nn + j] = (_Float16)p;
}

// ---- stage 2: out[b][i][l] = (adj[b] @ Gt^T)[i][l] / (adj[b] @ p)[i] / n
// adj comes from the 8.4 MB bit matrix (L2-resident): per tile each lane loads
// one uint4 (128 bits = BK=128 cols of its row) and expands its byte per
// K-subtile to a fp16 0/1 fragment. MFMA order identical to R6 -> bitwise
// identical output.  (UNCHANGED from R8 -- control for this round's A/B.)
__global__ __launch_bounds__(256) void k_agg(const uint4* __restrict__ Pk,
                                             const _Float16* __restrict__ Gt,
                                             float* __restrict__ out) {
  const int b = blockIdx.y;
  const int tid = threadIdx.x;
  const int lane = tid & 63;
  const int wv = tid >> 6;
  const int ln15 = lane & 15;
  const int quad = lane >> 4;
  const int i0 = blockIdx.x * 64 + wv * 16;

  const uint4* prow = Pk + ((size_t)b * Nn + i0 + ln15) * 32;   // 32 uint4 per packed row

  const _Float16* g0 = Gt + ((size_t)b * GTR + ln15) * Nn + quad * 8;
  const _Float16* g1 = g0 + (size_t)16 * Nn;
  const _Float16* g2 = g0 + (size_t)32 * Nn;
  const _Float16* g3 = g0 + (size_t)48 * Nn;
  const _Float16* g4 = g0 + (size_t)64 * Nn;

  f32x4 acc0 = {0,0,0,0}, acc1 = {0,0,0,0}, acc2 = {0,0,0,0}, acc3 = {0,0,0,0}, acc4 = {0,0,0,0};

  #pragma unroll 2
  for (int t = 0; t < NT; ++t) {
    const int k0 = t * 128;
    uint4 w4 = prow[t];                          // bits for cols k0..k0+127
    half8_t bg0[4], bg1[4], bg2[4], bg3[4], bg4[4];
    #pragma unroll
    for (int s = 0; s < 4; ++s) {
      const int kk = k0 + s * 32;
      bg0[s] = *(const half8_t*)(g0 + kk);
      bg1[s] = *(const half8_t*)(g1 + kk);
      bg2[s] = *(const half8_t*)(g2 + kk);
      bg3[s] = *(const half8_t*)(g3 + kk);
      bg4[s] = *(const half8_t*)(g4 + kk);
    }
    #pragma unroll
    for (int s = 0; s < 4; ++s) {
      const unsigned int word = (s == 0) ? w4.x : (s == 1) ? w4.y : (s == 2) ? w4.z : w4.w;
      half8_t aF = expand8((word >> (quad * 8)) & 0xffu);
      acc0 = __builtin_amdgcn_mfma_f32_16x16x32_f16(aF, bg0[s], acc0, 0, 0, 0);
      acc1 = __builtin_amdgcn_mfma_f32_16x16x32_f16(aF, bg1[s], acc1, 0, 0, 0);
      acc2 = __builtin_amdgcn_mfma_f32_16x16x32_f16(aF, bg2[s], acc2, 0, 0, 0);
      acc3 = __builtin_amdgcn_mfma_f32_16x16x32_f16(aF, bg3[s], acc3, 0, 0, 0);
      acc4 = __builtin_amdgcn_mfma_f32_16x16x32_f16(aF, bg4[s], acc4, 0, 0, 0);
    }
  }

  // denominator (col 64 = tile4 local col 0) held by lane (lane & 48); broadcast per row
  float den0 = __shfl(acc4[0], lane & 48);
  float den1 = __shfl(acc4[1], lane & 48);
  float den2 = __shfl(acc4[2], lane & 48);
  float den3 = __shfl(acc4[3], lane & 48);
  const float invn = 1.0f / (float)Nn;
  float* orow = out + ((size_t)b * Nn + i0) * OUTd;
  #pragma unroll
  for (int r = 0; r < 4; ++r) {
    float d = (r == 0) ? den0 : (r == 1) ? den1 : (r == 2) ? den2 : den3;
    float rd = invn / d;
    int ir = quad * 4 + r;
    orow[(size_t)ir * OUTd + 0  + ln15] = acc0[r] * rd;
    orow[(size_t)ir * OUTd + 16 + ln15] = acc1[r] * rd;
    orow[(size_t)ir * OUTd + 32 + ln15] = acc2[r] * rd;
    orow[(size_t)ir * OUTd + 48 + ln15] = acc3[r] * rd;
  }
}

extern "C" void kernel_launch(void* const* d_in, const int* in_sizes, int n_in,
                              void* d_out, int out_size, void* d_ws, size_t ws_size,
                              hipStream_t stream) {
  const float* feat   = (const float*)d_in[0];
  const float* adj    = (const float*)d_in[1];
  const float* W_fc   = (const float*)d_in[2];
  const float* b_fc   = (const float*)d_in[3];
  const float* W_attn = (const float*)d_in[4];
  (void)d_in[5]; // b_attn cancels in softmax
  float* out = (float*)d_out;

  char* ws = (char*)d_ws;
  _Float16* Gt = (_Float16*)ws;                               // 4*80*4096*2 = 2,621,440 B
  _Float16* Ut = (_Float16*)(ws + 2621440);                   // 80*256*2   =    40,960 B
  float*    hb  = (float*)(ws + 2621440 + 40960);             // 256 B
  float*    sb  = (float*)(ws + 2621440 + 40960 + 256);       // 4 B
  unsigned int* Pk32 = (unsigned int*)(ws + 4194304);         // 16384*128*4 = 8,388,608 B

  k_prep<<<66, 256, 0, stream>>>(W_fc, W_attn, b_fc, Ut, hb, sb);
  k_featpack<<<8448, 256, 0, stream>>>(feat, adj, Ut, hb, sb, Gt, Pk32);
  k_agg<<<dim3(64, 4), 256, 0, stream>>>((const uint4*)Pk32, Gt, out);
}

// Round 6
// 433.823 us; speedup vs baseline: 1.0918x; 1.0626x over previous
//
#include <hip/hip_runtime.h>
#include <stdint.h>
#include <math.h>

// GAT layer, restructured:
//   dst-term and b_attn cancel in softmax over j; masked exp()==0 exactly.
//   p_j = exp(src_j) (no max needed: |src|<~0.7), G = [p*hsum | p] in fp16,
//   out = (adj @ G_num) / (adj @ p) / n via f16 MFMA, adj converted on the fly.
// R10: nt-load A/B test. Ledger: six adj-reader structures all cap at
//      1.6-2.1 TB/s (pattern-independent) while fills write at 6.7 TB/s.
//      Theory: the 1 GiB workspace poison fill leaves L3 full of dirty lines;
//      every adj read allocation forces a dirty eviction -> paired HBM
//      writeback -> ~2x-3x effective traffic. Fix: __builtin_nontemporal_load
//      (nt bit, no L2/L3 allocation) on ALL adj reads. Structure otherwise
//      byte-identical to R0 (best: 412us, k_agg ~128us). Bitpack abandoned
//      (pack pass pays the same churn + extra kernel).

#define Bz   4
#define Nn   4096
#define Dd   256
#define OUTd 64
#define GTR  80   // 64 hsum rows + 1 p row + 15 pad rows (poison; cols 65..79 ignored)

typedef float    f32x4   __attribute__((ext_vector_type(4)));
typedef __fp16   fp16x2  __attribute__((ext_vector_type(2)));   // cvt_pkrtz return type
typedef _Float16 half8_t __attribute__((ext_vector_type(8)));

__device__ inline half8_t cvt8(f32x4 a, f32x4 b) {
  union { fp16x2 h2[4]; half8_t h8; } r;
  r.h2[0] = __builtin_amdgcn_cvt_pkrtz(a[0], a[1]);
  r.h2[1] = __builtin_amdgcn_cvt_pkrtz(a[2], a[3]);
  r.h2[2] = __builtin_amdgcn_cvt_pkrtz(b[0], b[1]);
  r.h2[3] = __builtin_amdgcn_cvt_pkrtz(b[2], b[3]);
  return r.h8;
}

// ---- prep (merged): Ut rows 0..63 (head-summed W_fc), Ut row 64 (src vector),
//      hb[l] = sum_h b_fc, sb = b_fc . w_s.  w_s recomputed in blocks 64/65.
__global__ __launch_bounds__(256) void k_prep(const float* __restrict__ W_fc,
                                              const float* __restrict__ W_attn,
                                              const float* __restrict__ b_fc,
                                              _Float16* __restrict__ Ut,
                                              float* __restrict__ hb,
                                              float* __restrict__ sb) {
  const int bx = blockIdx.x, t = threadIdx.x;
  if (bx < 64) {
    const int l = bx, d = t;
    float v = W_fc[l * 256 + d] + W_fc[(64 + l) * 256 + d] +
              W_fc[(128 + l) * 256 + d] + W_fc[(192 + l) * 256 + d];
    Ut[l * 256 + d] = (_Float16)v;
    return;
  }
  __shared__ float ws_sh[256];   // w_s[ho], ho = h*64+o
  {
    const int h = t >> 6, o = t & 63;
    float s = 0.f;
    for (int k = 0; k < 4; ++k) s += W_attn[k * 512 + h * 128 + o];
    ws_sh[t] = s * 0.25f;
  }
  __syncthreads();
  if (bx == 64) {
    const int d = t;
    float v = 0.f;
    for (int ho = 0; ho < 256; ++ho) v += W_fc[ho * 256 + d] * ws_sh[ho];
    Ut[64 * 256 + d] = (_Float16)v;
  } else {
    __shared__ float red[256];
    red[t] = b_fc[t] * ws_sh[t];
    if (t < 64) hb[t] = b_fc[t] + b_fc[64 + t] + b_fc[128 + t] + b_fc[192 + t];
    __syncthreads();
    if (t == 0) {
      float a = 0.f;
      for (int i = 0; i < 256; ++i) a += red[i];
      *sb = a;
    }
  }
}

// ---- stage 1: Gt[b][l][j] = fp16(p_j * hsum_lj), Gt[b][64][j] = fp16(p_j)
__global__ __launch_bounds__(256) void k_feat(const float* __restrict__ feat,
                                              const _Float16* __restrict__ Ut,
                                              const float* __restrict__ hb,
                                              const float* __restrict__ sb,
                                              _Float16* __restrict__ Gt) {
  const int b = blockIdx.y;
  const int tid = threadIdx.x;
  const int lane = tid & 63;
  const int wv = tid >> 6;
  const int ln15 = lane & 15;
  const int quad = lane >> 4;
  const int j = blockIdx.x * 64 + wv * 16 + ln15;

  const float* frow = feat + ((size_t)b * Nn + j) * Dd + quad * 8;
  f32x4 acc0 = {0,0,0,0}, acc1 = {0,0,0,0}, acc2 = {0,0,0,0}, acc3 = {0,0,0,0}, acc4 = {0,0,0,0};

  #pragma unroll
  for (int d0 = 0; d0 < Dd; d0 += 32) {
    f32x4 F0 = *(const f32x4*)(frow + d0);
    f32x4 F1 = *(const f32x4*)(frow + d0 + 4);
    half8_t bf = cvt8(F0, F1);
    const _Float16* up = Ut + (size_t)ln15 * Dd + d0 + quad * 8;
    acc0 = __builtin_amdgcn_mfma_f32_16x16x32_f16(*(const half8_t*)(up + 0 * 16 * Dd), bf, acc0, 0, 0, 0);
    acc1 = __builtin_amdgcn_mfma_f32_16x16x32_f16(*(const half8_t*)(up + 1 * 16 * Dd), bf, acc1, 0, 0, 0);
    acc2 = __builtin_amdgcn_mfma_f32_16x16x32_f16(*(const half8_t*)(up + 2 * 16 * Dd), bf, acc2, 0, 0, 0);
    acc3 = __builtin_amdgcn_mfma_f32_16x16x32_f16(*(const half8_t*)(up + 3 * 16 * Dd), bf, acc3, 0, 0, 0);
    acc4 = __builtin_amdgcn_mfma_f32_16x16x32_f16(*(const half8_t*)(up + 4 * 16 * Dd), bf, acc4, 0, 0, 0);
  }
  float srcv = __shfl(acc4[0], ln15) + sb[0];
  float p = expf(srcv);
  _Float16* gb = Gt + (size_t)b * GTR * Nn;
  #pragma unroll
  for (int r = 0; r < 4; ++r) {
    int lb = quad * 4 + r;
    gb[(size_t)(0  + lb) * Nn + j] = (_Float16)((acc0[r] + hb[0  + lb]) * p);
    gb[(size_t)(16 + lb) * Nn + j] = (_Float16)((acc1[r] + hb[16 + lb]) * p);
    gb[(size_t)(32 + lb) * Nn + j] = (_Float16)((acc2[r] + hb[32 + lb]) * p);
    gb[(size_t)(48 + lb) * Nn + j] = (_Float16)((acc3[r] + hb[48 + lb]) * p);
  }
  if (quad == 0) gb[(size_t)64 * Nn + j] = (_Float16)p;
}

// ---- stage 2: out[b][i][l] = (adj[b] @ Gt^T)[i][l] / (adj[b] @ p)[i] / n
// Per wave: 16 rows (i) x 80 cols; A = adj tile loaded global->reg in frag
// layout via NON-TEMPORAL loads (no L3 allocation -> no dirty-poison
// evictions), cvt to fp16. MFMA order identical to R0 -> bitwise-same output.
__global__ __launch_bounds__(256) void k_agg(const float* __restrict__ adj,
                                             const _Float16* __restrict__ Gt,
                                             float* __restrict__ out) {
  const int b = blockIdx.y;
  const int tid = threadIdx.x;
  const int lane = tid & 63;
  const int wv = tid >> 6;
  const int ln15 = lane & 15;
  const int quad = lane >> 4;
  const int i0 = blockIdx.x * 64 + wv * 16;

  const float* arow = adj + ((size_t)b * Nn + (i0 + ln15)) * (size_t)Nn + quad * 8;
  const _Float16* g0 = Gt + ((size_t)b * GTR + ln15) * Nn + quad * 8;
  const _Float16* g1 = g0 + (size_t)16 * Nn;
  const _Float16* g2 = g0 + (size_t)32 * Nn;
  const _Float16* g3 = g0 + (size_t)48 * Nn;
  const _Float16* g4 = g0 + (size_t)64 * Nn;

  f32x4 acc0 = {0,0,0,0}, acc1 = {0,0,0,0}, acc2 = {0,0,0,0}, acc3 = {0,0,0,0}, acc4 = {0,0,0,0};

  for (int k0 = 0; k0 < Nn; k0 += 64) {
    f32x4 A0 = __builtin_nontemporal_load((const f32x4*)(arow + k0));
    f32x4 A1 = __builtin_nontemporal_load((const f32x4*)(arow + k0 + 4));
    f32x4 A2 = __builtin_nontemporal_load((const f32x4*)(arow + k0 + 32));
    f32x4 A3 = __builtin_nontemporal_load((const f32x4*)(arow + k0 + 36));
    half8_t b00 = *(const half8_t*)(g0 + k0);
    half8_t b01 = *(const half8_t*)(g1 + k0);
    half8_t b02 = *(const half8_t*)(g2 + k0);
    half8_t b03 = *(const half8_t*)(g3 + k0);
    half8_t b04 = *(const half8_t*)(g4 + k0);
    half8_t b10 = *(const half8_t*)(g0 + k0 + 32);
    half8_t b11 = *(const half8_t*)(g1 + k0 + 32);
    half8_t b12 = *(const half8_t*)(g2 + k0 + 32);
    half8_t b13 = *(const half8_t*)(g3 + k0 + 32);
    half8_t b14 = *(const half8_t*)(g4 + k0 + 32);
    half8_t aF0 = cvt8(A0, A1);   // adj is exactly 0/1 -> exact in fp16
    half8_t aF1 = cvt8(A2, A3);
    acc0 = __builtin_amdgcn_mfma_f32_16x16x32_f16(aF0, b00, acc0, 0, 0, 0);
    acc1 = __builtin_amdgcn_mfma_f32_16x16x32_f16(aF0, b01, acc1, 0, 0, 0);
    acc2 = __builtin_amdgcn_mfma_f32_16x16x32_f16(aF0, b02, acc2, 0, 0, 0);
    acc3 = __builtin_amdgcn_mfma_f32_16x16x32_f16(aF0, b03, acc3, 0, 0, 0);
    acc4 = __builtin_amdgcn_mfma_f32_16x16x32_f16(aF0, b04, acc4, 0, 0, 0);
    acc0 = __builtin_amdgcn_mfma_f32_16x16x32_f16(aF1, b10, acc0, 0, 0, 0);
    acc1 = __builtin_amdgcn_mfma_f32_16x16x32_f16(aF1, b11, acc1, 0, 0, 0);
    acc2 = __builtin_amdgcn_mfma_f32_16x16x32_f16(aF1, b12, acc2, 0, 0, 0);
    acc3 = __builtin_amdgcn_mfma_f32_16x16x32_f16(aF1, b13, acc3, 0, 0, 0);
    acc4 = __builtin_amdgcn_mfma_f32_16x16x32_f16(aF1, b14, acc4, 0, 0, 0);
  }

  // denominator (col 64 = tile4 local col 0) held by lane (lane & 48); broadcast per row
  float den0 = __shfl(acc4[0], lane & 48);
  float den1 = __shfl(acc4[1], lane & 48);
  float den2 = __shfl(acc4[2], lane & 48);
  float den3 = __shfl(acc4[3], lane & 48);
  const float invn = 1.0f / (float)Nn;
  float* orow = out + ((size_t)b * Nn + i0) * OUTd;
  #pragma unroll
  for (int r = 0; r < 4; ++r) {
    float d = (r == 0) ? den0 : (r == 1) ? den1 : (r == 2) ? den2 : den3;
    float rd = invn / d;
    int ir = quad * 4 + r;
    orow[(size_t)ir * OUTd + 0  + ln15] = acc0[r] * rd;
    orow[(size_t)ir * OUTd + 16 + ln15] = acc1[r] * rd;
    orow[(size_t)ir * OUTd + 32 + ln15] = acc2[r] * rd;
    orow[(size_t)ir * OUTd + 48 + ln15] = acc3[r] * rd;
  }
}

extern "C" void kernel_launch(void* const* d_in, const int* in_sizes, int n_in,
                              void* d_out, int out_size, void* d_ws, size_t ws_size,
                              hipStream_t stream) {
  const float* feat   = (const float*)d_in[0];
  const float* adj    = (const float*)d_in[1];
  const float* W_fc   = (const float*)d_in[2];
  const float* b_fc   = (const float*)d_in[3];
  const float* W_attn = (const float*)d_in[4];
  (void)d_in[5]; // b_attn cancels in softmax
  float* out = (float*)d_out;

  char* ws = (char*)d_ws;
  _Float16* Gt = (_Float16*)ws;                               // 4*80*4096*2 = 2,621,440 B
  _Float16* Ut = (_Float16*)(ws + 2621440);                   // 80*256*2   =    40,960 B
  float*    hb  = (float*)(ws + 2621440 + 40960);             // 256 B
  float*    sb  = (float*)(ws + 2621440 + 40960 + 256);       // 4 B

  k_prep<<<66, 256, 0, stream>>>(W_fc, W_attn, b_fc, Ut, hb, sb);
  k_feat<<<dim3(64, 4), 256, 0, stream>>>(feat, Ut, hb, sb, Gt);
  k_agg<<<dim3(64, 4), 256, 0, stream>>>(adj, Gt, out);
}

// Round 7
// 411.211 us; speedup vs baseline: 1.1518x; 1.0550x over previous
//
#include <hip/hip_runtime.h>
#include <stdint.h>
#include <math.h>

// GAT layer, restructured:
//   dst-term and b_attn cancel in softmax over j; masked exp()==0 exactly.
//   p_j = exp(src_j) (no max needed: |src|<~0.7), G = [p*hsum | p] in fp16,
//   out = (adj @ G_num) / (adj @ p) / n via f16 MFMA, adj converted on the fly.
// R11 (terminal): revert to tied-best R0 structure (412.0 us; R6's async
//   variant tied at 411.7). Eight adj-reader structures (direct / split-K /
//   async-dbuf / nt / 3x bitpack) all cap at 1.6-2.1 TB/s pattern-
//   independently; floor = 268 MB adj / 2.1 TB/s ~= 128 us (k_agg) +
//   ~284 us harness-fixed content. This kernel sits at that floor.

#define Bz   4
#define Nn   4096
#define Dd   256
#define OUTd 64
#define GTR  80   // 64 hsum rows + 1 p row + 15 pad rows (poison; cols 65..79 ignored)

typedef float    f32x4   __attribute__((ext_vector_type(4)));
typedef __fp16   fp16x2  __attribute__((ext_vector_type(2)));   // cvt_pkrtz return type
typedef _Float16 half8_t __attribute__((ext_vector_type(8)));

__device__ inline half8_t cvt8(float4 a, float4 b) {
  union { fp16x2 h2[4]; half8_t h8; } r;
  r.h2[0] = __builtin_amdgcn_cvt_pkrtz(a.x, a.y);
  r.h2[1] = __builtin_amdgcn_cvt_pkrtz(a.z, a.w);
  r.h2[2] = __builtin_amdgcn_cvt_pkrtz(b.x, b.y);
  r.h2[3] = __builtin_amdgcn_cvt_pkrtz(b.z, b.w);
  return r.h8;
}

// ---- prep (merged): Ut rows 0..63 (head-summed W_fc), Ut row 64 (src vector),
//      hb[l] = sum_h b_fc, sb = b_fc . w_s.  w_s recomputed in blocks 64/65.
__global__ __launch_bounds__(256) void k_prep(const float* __restrict__ W_fc,
                                              const float* __restrict__ W_attn,
                                              const float* __restrict__ b_fc,
                                              _Float16* __restrict__ Ut,
                                              float* __restrict__ hb,
                                              float* __restrict__ sb) {
  const int bx = blockIdx.x, t = threadIdx.x;
  if (bx < 64) {
    const int l = bx, d = t;
    float v = W_fc[l * 256 + d] + W_fc[(64 + l) * 256 + d] +
              W_fc[(128 + l) * 256 + d] + W_fc[(192 + l) * 256 + d];
    Ut[l * 256 + d] = (_Float16)v;
    return;
  }
  __shared__ float ws_sh[256];   // w_s[ho], ho = h*64+o
  {
    const int h = t >> 6, o = t & 63;
    float s = 0.f;
    for (int k = 0; k < 4; ++k) s += W_attn[k * 512 + h * 128 + o];
    ws_sh[t] = s * 0.25f;
  }
  __syncthreads();
  if (bx == 64) {
    const int d = t;
    float v = 0.f;
    for (int ho = 0; ho < 256; ++ho) v += W_fc[ho * 256 + d] * ws_sh[ho];
    Ut[64 * 256 + d] = (_Float16)v;
  } else {
    __shared__ float red[256];
    red[t] = b_fc[t] * ws_sh[t];
    if (t < 64) hb[t] = b_fc[t] + b_fc[64 + t] + b_fc[128 + t] + b_fc[192 + t];
    __syncthreads();
    if (t == 0) {
      float a = 0.f;
      for (int i = 0; i < 256; ++i) a += red[i];
      *sb = a;
    }
  }
}

// ---- stage 1: Gt[b][l][j] = fp16(p_j * hsum_lj), Gt[b][64][j] = fp16(p_j)
__global__ __launch_bounds__(256) void k_feat(const float* __restrict__ feat,
                                              const _Float16* __restrict__ Ut,
                                              const float* __restrict__ hb,
                                              const float* __restrict__ sb,
                                              _Float16* __restrict__ Gt) {
  const int b = blockIdx.y;
  const int tid = threadIdx.x;
  const int lane = tid & 63;
  const int wv = tid >> 6;
  const int ln15 = lane & 15;
  const int quad = lane >> 4;
  const int j = blockIdx.x * 64 + wv * 16 + ln15;

  const float* frow = feat + ((size_t)b * Nn + j) * Dd + quad * 8;
  f32x4 acc0 = {0,0,0,0}, acc1 = {0,0,0,0}, acc2 = {0,0,0,0}, acc3 = {0,0,0,0}, acc4 = {0,0,0,0};

  #pragma unroll
  for (int d0 = 0; d0 < Dd; d0 += 32) {
    float4 F0 = *(const float4*)(frow + d0);
    float4 F1 = *(const float4*)(frow + d0 + 4);
    half8_t bf = cvt8(F0, F1);
    const _Float16* up = Ut + (size_t)ln15 * Dd + d0 + quad * 8;
    acc0 = __builtin_amdgcn_mfma_f32_16x16x32_f16(*(const half8_t*)(up + 0 * 16 * Dd), bf, acc0, 0, 0, 0);
    acc1 = __builtin_amdgcn_mfma_f32_16x16x32_f16(*(const half8_t*)(up + 1 * 16 * Dd), bf, acc1, 0, 0, 0);
    acc2 = __builtin_amdgcn_mfma_f32_16x16x32_f16(*(const half8_t*)(up + 2 * 16 * Dd), bf, acc2, 0, 0, 0);
    acc3 = __builtin_amdgcn_mfma_f32_16x16x32_f16(*(const half8_t*)(up + 3 * 16 * Dd), bf, acc3, 0, 0, 0);
    acc4 = __builtin_amdgcn_mfma_f32_16x16x32_f16(*(const half8_t*)(up + 4 * 16 * Dd), bf, acc4, 0, 0, 0);
  }
  float srcv = __shfl(acc4[0], ln15) + sb[0];
  float p = expf(srcv);
  _Float16* gb = Gt + (size_t)b * GTR * Nn;
  #pragma unroll
  for (int r = 0; r < 4; ++r) {
    int lb = quad * 4 + r;
    gb[(size_t)(0  + lb) * Nn + j] = (_Float16)((acc0[r] + hb[0  + lb]) * p);
    gb[(size_t)(16 + lb) * Nn + j] = (_Float16)((acc1[r] + hb[16 + lb]) * p);
    gb[(size_t)(32 + lb) * Nn + j] = (_Float16)((acc2[r] + hb[32 + lb]) * p);
    gb[(size_t)(48 + lb) * Nn + j] = (_Float16)((acc3[r] + hb[48 + lb]) * p);
  }
  if (quad == 0) gb[(size_t)64 * Nn + j] = (_Float16)p;
}

// ---- stage 2: out[b][i][l] = (adj[b] @ Gt^T)[i][l] / (adj[b] @ p)[i] / n
// Per wave: 16 rows (i) x 80 cols; A = adj tile loaded global->reg in frag layout, cvt to fp16.
__global__ __launch_bounds__(256) void k_agg(const float* __restrict__ adj,
                                             const _Float16* __restrict__ Gt,
                                             float* __restrict__ out) {
  const int b = blockIdx.y;
  const int tid = threadIdx.x;
  const int lane = tid & 63;
  const int wv = tid >> 6;
  const int ln15 = lane & 15;
  const int quad = lane >> 4;
  const int i0 = blockIdx.x * 64 + wv * 16;

  const float* arow = adj + ((size_t)b * Nn + (i0 + ln15)) * (size_t)Nn + quad * 8;
  const _Float16* g0 = Gt + ((size_t)b * GTR + ln15) * Nn + quad * 8;
  const _Float16* g1 = g0 + (size_t)16 * Nn;
  const _Float16* g2 = g0 + (size_t)32 * Nn;
  const _Float16* g3 = g0 + (size_t)48 * Nn;
  const _Float16* g4 = g0 + (size_t)64 * Nn;

  f32x4 acc0 = {0,0,0,0}, acc1 = {0,0,0,0}, acc2 = {0,0,0,0}, acc3 = {0,0,0,0}, acc4 = {0,0,0,0};

  for (int k0 = 0; k0 < Nn; k0 += 64) {
    float4 A0 = *(const float4*)(arow + k0);
    float4 A1 = *(const float4*)(arow + k0 + 4);
    float4 A2 = *(const float4*)(arow + k0 + 32);
    float4 A3 = *(const float4*)(arow + k0 + 36);
    half8_t b00 = *(const half8_t*)(g0 + k0);
    half8_t b01 = *(const half8_t*)(g1 + k0);
    half8_t b02 = *(const half8_t*)(g2 + k0);
    half8_t b03 = *(const half8_t*)(g3 + k0);
    half8_t b04 = *(const half8_t*)(g4 + k0);
    half8_t b10 = *(const half8_t*)(g0 + k0 + 32);
    half8_t b11 = *(const half8_t*)(g1 + k0 + 32);
    half8_t b12 = *(const half8_t*)(g2 + k0 + 32);
    half8_t b13 = *(const half8_t*)(g3 + k0 + 32);
    half8_t b14 = *(const half8_t*)(g4 + k0 + 32);
    half8_t aF0 = cvt8(A0, A1);   // adj is exactly 0/1 -> exact in fp16
    half8_t aF1 = cvt8(A2, A3);
    acc0 = __builtin_amdgcn_mfma_f32_16x16x32_f16(aF0, b00, acc0, 0, 0, 0);
    acc1 = __builtin_amdgcn_mfma_f32_16x16x32_f16(aF0, b01, acc1, 0, 0, 0);
    acc2 = __builtin_amdgcn_mfma_f32_16x16x32_f16(aF0, b02, acc2, 0, 0, 0);
    acc3 = __builtin_amdgcn_mfma_f32_16x16x32_f16(aF0, b03, acc3, 0, 0, 0);
    acc4 = __builtin_amdgcn_mfma_f32_16x16x32_f16(aF0, b04, acc4, 0, 0, 0);
    acc0 = __builtin_amdgcn_mfma_f32_16x16x32_f16(aF1, b10, acc0, 0, 0, 0);
    acc1 = __builtin_amdgcn_mfma_f32_16x16x32_f16(aF1, b11, acc1, 0, 0, 0);
    acc2 = __builtin_amdgcn_mfma_f32_16x16x32_f16(aF1, b12, acc2, 0, 0, 0);
    acc3 = __builtin_amdgcn_mfma_f32_16x16x32_f16(aF1, b13, acc3, 0, 0, 0);
    acc4 = __builtin_amdgcn_mfma_f32_16x16x32_f16(aF1, b14, acc4, 0, 0, 0);
  }

  // denominator (col 64 = tile4 local col 0) held by lane (lane & 48); broadcast per row
  float den0 = __shfl(acc4[0], lane & 48);
  float den1 = __shfl(acc4[1], lane & 48);
  float den2 = __shfl(acc4[2], lane & 48);
  float den3 = __shfl(acc4[3], lane & 48);
  const float invn = 1.0f / (float)Nn;
  float* orow = out + ((size_t)b * Nn + i0) * OUTd;
  #pragma unroll
  for (int r = 0; r < 4; ++r) {
    float d = (r == 0) ? den0 : (r == 1) ? den1 : (r == 2) ? den2 : den3;
    float rd = invn / d;
    int ir = quad * 4 + r;
    orow[(size_t)ir * OUTd + 0  + ln15] = acc0[r] * rd;
    orow[(size_t)ir * OUTd + 16 + ln15] = acc1[r] * rd;
    orow[(size_t)ir * OUTd + 32 + ln15] = acc2[r] * rd;
    orow[(size_t)ir * OUTd + 48 + ln15] = acc3[r] * rd;
  }
}

extern "C" void kernel_launch(void* const* d_in, const int* in_sizes, int n_in,
                              void* d_out, int out_size, void* d_ws, size_t ws_size,
                              hipStream_t stream) {
  const float* feat   = (const float*)d_in[0];
  const float* adj    = (const float*)d_in[1];
  const float* W_fc   = (const float*)d_in[2];
  const float* b_fc   = (const float*)d_in[3];
  const float* W_attn = (const float*)d_in[4];
  (void)d_in[5]; // b_attn cancels in softmax
  float* out = (float*)d_out;

  char* ws = (char*)d_ws;
  _Float16* Gt = (_Float16*)ws;                               // 4*80*4096*2 = 2,621,440 B
  _Float16* Ut = (_Float16*)(ws + 2621440);                   // 80*256*2   =    40,960 B
  float*    hb  = (float*)(ws + 2621440 + 40960);             // 256 B
  float*    sb  = (float*)(ws + 2621440 + 40960 + 256);       // 4 B

  k_prep<<<66, 256, 0, stream>>>(W_fc, W_attn, b_fc, Ut, hb, sb);
  k_feat<<<dim3(64, 4), 256, 0, stream>>>(feat, Ut, hb, sb, Gt);
  k_agg<<<dim3(64, 4), 256, 0, stream>>>(adj, Gt, out);
}